// Round 8
// baseline (515.472 us; speedup 1.0000x reference)
//
#include <hip/hip_runtime.h>
#include <hip/hip_bf16.h>
#include <hip/hip_fp16.h>

// RelMultiHeadDotProductAttention (Transformer-XL rel attention)
// B=2 S=2048 D=1024 H=16 Dh=64 F=1024. fp32 in/out; internal bf16 MFMA.
// Round 14: 3 WG/CU for real. R13 was clean but stuck at 2 WG: 64 VGPR + 32
// AGPR = 96 unified regs > 85 (6 waves/SIMD threshold). Fix: eliminate Qr
// algebraically — (q+rr)·rpos_j = (q+rw)·rpos_j + [drr_h·rpos_j], the bracket
// is per-(h,j) scalar -> precompute drp[16][2048] fp32 (tiny kernel) and add
// in A-phase as one float4 load. bqr gone: persistent 96 -> 80 regs; peak
// live ~82 fits __launch_bounds__(512,6)'s 84-reg cap -> forced 3 WG/CU
// (LDS 3x34.3 = 103 KB OK). q-GEMM now single-output (-8 MB traffic).
// Also: gemm_bt staging via global_load_lds width=16 (staging layout is
// exactly base + tid*16B; m193 +67% on staging-bound GEMM).
// Spill tripwire: attn WRITE_SIZE must stay ~8.2 MB.

#define B_  2
#define S_  2048
#define D_  1024
#define H_  16
#define DH_ 64
#define HD_ 1024
#define F_  1024
#define N_  4096   // B*S
#define KC_ 512    // k-chunk
#define SP2 516    // chunk row stride (fp16): 258 dw = 2 mod 32 banks
#define KQSC 0.1803368801111204f  // log2(e)/8, folded into qw (and drp)

typedef __attribute__((ext_vector_type(8))) short  short8;   // 8 x bf16 (4 VGPRs)
typedef __attribute__((ext_vector_type(4))) float  floatx4;
typedef __attribute__((ext_vector_type(4))) unsigned int uintx4;

__device__ __forceinline__ unsigned short f2bf(float x) {
  unsigned u = __float_as_uint(x);
  u += 0x7FFFu + ((u >> 16) & 1u);          // RNE
  return (unsigned short)(u >> 16);
}
__device__ __forceinline__ unsigned short f2h(float x) {
  __half h = __float2half(x);
  unsigned short u; __builtin_memcpy(&u, &h, 2);
  return u;
}
__device__ __forceinline__ float h2f(unsigned short u) {
  __half h; __builtin_memcpy(&h, &u, 2);
  return __half2float(h);
}
__device__ __forceinline__ float bf2f(unsigned short u) {
  return __uint_as_float(((unsigned)u) << 16);
}

// async global->LDS, 16B per lane (dest must be linear base + lane*16)
__device__ __forceinline__ void gld_lds16(const void* g, void* l) {
  __builtin_amdgcn_global_load_lds(
      (const __attribute__((address_space(1))) unsigned int*)g,
      (__attribute__((address_space(3))) unsigned int*)l, 16, 0, 0);
}

// ------- prep: fp32->bf16 casts (q, kv, pos) + 5 weight transposes, ONE launch -------
#define CQ_ (N_ * D_ / 4)   // 1048576 float4 units each for q, kv
#define CAST_BLKS 10240     // (2*CQ_ + S_*D_/4) / 256
struct PrepP {
  const float* sq; const float* skv; const float* spos;
  unsigned short* dq; unsigned short* dkv; unsigned short* dpos;
  const float* ts[5]; unsigned short* td[5];
};
__global__ void prep_all(PrepP p) {
  __shared__ float t[32][33];
  int bid = blockIdx.x;
  int tid = threadIdx.x;
  if (bid < CAST_BLKS) {
    int i = bid * 256 + tid;
    const float* s; unsigned short* d; int off;
    if (i < CQ_)            { s = p.sq;   d = p.dq;   off = i; }
    else if (i < 2 * CQ_)   { s = p.skv;  d = p.dkv;  off = i - CQ_; }
    else                    { s = p.spos; d = p.dpos; off = i - 2 * CQ_; }
    float4 v = ((const float4*)s)[off];
    ((ushort4*)d)[off] = make_ushort4(f2bf(v.x), f2bf(v.y), f2bf(v.z), f2bf(v.w));
  } else {
    int b2 = bid - CAST_BLKS;               // 0..5119: 5 matrices x 32x32 tiles
    int z = b2 >> 10, y = (b2 >> 5) & 31, x = b2 & 31;
    const float* src = p.ts[z];
    unsigned short* dst = p.td[z];
    int c0 = x * 32, r0 = y * 32;
    int tx = tid & 31, ty = tid >> 5;       // (32,8)
#pragma unroll
    for (int i = 0; i < 4; i++)
      t[ty + i * 8][tx] = src[(size_t)(r0 + ty + i * 8) * 1024 + c0 + tx];
    __syncthreads();
#pragma unroll
    for (int i = 0; i < 4; i++)
      dst[(size_t)(c0 + ty + i * 8) * 1024 + r0 + tx] = f2bf(t[tx][ty + i * 8]);
  }
}

// ------- drp[h][j] = KQSC * sum_k (rrb-rwb)[h][k] * rpos[j][h][k] -------
// 32768 threads: one (j,h) each; rbp is bf16 [j][h][k].
__global__ void drp_kernel(const unsigned short* __restrict__ rbp,
                           const float* __restrict__ rrb, const float* __restrict__ rwb,
                           float* __restrict__ drp) {
  int idx = blockIdx.x * 256 + threadIdx.x;
  int j = idx >> 4, h = idx & 15;
  const unsigned short* rp = rbp + (size_t)j * HD_ + h * 64;
  const float* pa = rrb + h * 64;
  const float* pb = rwb + h * 64;
  float s = 0.f;
#pragma unroll
  for (int k = 0; k < 64; k += 8) {
    short8 v = *(const short8*)(rp + k);
#pragma unroll
    for (int e = 0; e < 8; e++)
      s += (pa[k + e] - pb[k + e]) * bf2f((unsigned short)v[e]);
  }
  drp[h * 2048 + j] = s * KQSC;
}

// ---------------- bf16 GEMM, C = A[M][K] * Bt[N][K]^T + bias ----------------
// 4-segment dispatch: block bx picks segment by bend boundaries (monotone).
// mode 0: outA bf16 = acc + bias
// mode 1: outA bf16 = (acc+bias+b2a)*KQSC
// mode 2: outF fp32 = acc + bias
// mode 4: bf16, written directly in vt layout [b][h][dh][s]
// Staging via global_load_lds width=16 (dest linear: elem off = tid*8 = tid*16B).
struct GSeg {
  const unsigned short* A; const unsigned short* Bt;
  const float* bias; const float* b2a;
  unsigned short* outA; float* outF;
  int mode; int bend;
};
struct GP { GSeg s[4]; };
__launch_bounds__(256, 2)
__global__ void gemm_bt(GP p, int Nn, int K) {
  __shared__ unsigned short As[128 * 64];
  __shared__ unsigned short Bs[128 * 64];
  int bx = blockIdx.x;
  GSeg g = p.s[0]; int base = 0;
  if (bx >= p.s[0].bend) { g = p.s[1]; base = p.s[0].bend; }
  if (bx >= p.s[1].bend) { g = p.s[2]; base = p.s[1].bend; }
  if (bx >= p.s[2].bend) { g = p.s[3]; base = p.s[2].bend; }
  bx -= base;
  int nb = Nn >> 7;
  int bm = bx / nb, bn = bx % nb;
  int tid = threadIdx.x;
  int lane = tid & 63, wv = tid >> 6;
  int wm = wv >> 1, wn = wv & 1;
  int lm = lane & 15, lg = lane >> 4;
  const unsigned short* Ab = g.A + (size_t)(bm * 128) * K;
  const unsigned short* Bb = g.Bt + (size_t)(bn * 128) * K;
  floatx4 acc[4][4];
#pragma unroll
  for (int i = 0; i < 4; i++)
#pragma unroll
    for (int j = 0; j < 4; j++) acc[i][j] = (floatx4){0.f, 0.f, 0.f, 0.f};

  int lr = tid >> 3;          // 0..31 staging row
  int lc = (tid & 7) * 8;     // staging col (8 bf16 = 16B)
  for (int k0 = 0; k0 < K; k0 += 64) {
    __syncthreads();
#pragma unroll
    for (int i = 0; i < 4; i++) {
      int r = i * 32 + lr;
      gld_lds16(&Ab[(size_t)r * K + k0 + lc], &As[r * 64 + lc]);
      gld_lds16(&Bb[(size_t)r * K + k0 + lc], &Bs[r * 64 + lc]);
    }
    __syncthreads();
#pragma unroll
    for (int kk = 0; kk < 2; kk++) {
      short8 af[4], bf[4];
#pragma unroll
      for (int i = 0; i < 4; i++)
        af[i] = *(const short8*)&As[(wm * 64 + i * 16 + lm) * 64 + kk * 32 + lg * 8];
#pragma unroll
      for (int j = 0; j < 4; j++)
        bf[j] = *(const short8*)&Bs[(wn * 64 + j * 16 + lm) * 64 + kk * 32 + lg * 8];
#pragma unroll
      for (int i = 0; i < 4; i++)
#pragma unroll
        for (int j = 0; j < 4; j++)
          acc[i][j] = __builtin_amdgcn_mfma_f32_16x16x32_bf16(af[i], bf[j], acc[i][j], 0, 0, 0);
    }
  }
  // epilogue: C/D layout col=lane&15, row=(lane>>4)*4+reg  [m89/m91 verified]
#pragma unroll
  for (int j = 0; j < 4; j++) {
    int col = bn * 128 + wn * 64 + j * 16 + lm;
    float bs = g.bias ? g.bias[col] : 0.f;
    float ba = g.b2a ? g.b2a[col] : 0.f;
#pragma unroll
    for (int i = 0; i < 4; i++) {
      int row0 = bm * 128 + wm * 64 + i * 16 + lg * 4;
      if (g.mode == 4) {
        // vt[b][h][dh][s]: 4 consecutive s -> vector store
        int s = row0 & 2047, bb2 = row0 >> 11;
        size_t vidx = (((size_t)bb2 * H_ + (col >> 6)) * 64 + (col & 63)) * (size_t)S_ + s;
        ushort4 o = make_ushort4(f2bf(acc[i][j][0] + bs), f2bf(acc[i][j][1] + bs),
                                 f2bf(acc[i][j][2] + bs), f2bf(acc[i][j][3] + bs));
        *(ushort4*)&g.outA[vidx] = o;
      } else {
#pragma unroll
        for (int r = 0; r < 4; r++) {
          float v = acc[i][j][r] + bs;
          size_t idx = (size_t)(row0 + r) * Nn + col;
          if (g.mode == 0)      g.outA[idx] = f2bf(v);
          else if (g.mode == 1) g.outA[idx] = f2bf((v + ba) * KQSC);
          else                  g.outF[idx] = v;
        }
      }
    }
  }
}

// ---------------- fused rel-attention per (b, h, 32-query tile) ----------------
// R13 body minus Qr (drp precomputed): 512 threads = 8 waves, 34.2 KiB LDS.
// Persistent regs: acc 32 (AGPR) + bqw 16 -> fits (512,6)'s 84-reg cap ->
// 3 WG/CU forced. Per chunk (4 chunks of 512), wave wv owns k-share
// [wv*64, wv*64+64):
//   A(c): rpos.Qw^T MFMA + drp[h][j] (float4 load), scatter fp16 into score
//   barrier; B'(c): K.Qw^T + R + exp2 + sum (regs), P bf16 in place (cvt_pk)
//   D(c): O += P V (own-wave P cols, same-wave program order, no barrier)
//   barrier (all D reads done before next chunk's A overwrites the buffer)
// Tail: cross-wave sum reduce; two-pass 8->4->1 O reduce (32 KB fits buffer).
__launch_bounds__(512, 6)
__global__ void attn_kernel(const unsigned short* __restrict__ qw,
                            const unsigned short* __restrict__ kb,
                            const unsigned short* __restrict__ rb,
                            const unsigned short* __restrict__ vt,
                            const float* __restrict__ drp,
                            unsigned short* __restrict__ xb) {
  __shared__ __align__(16) unsigned short sS[32 * SP2];  // single score chunk (33 KB)
  __shared__ float sSum[8][32];
  __shared__ float sLinv[32];
  int bid = blockIdx.x;                 // 2048 = 32 bh * 64 qt
  int l = ((bid & 7) << 8) | (bid >> 3);  // XCD swizzle: xcd gets 4 whole bh
  int qt = l & 63;
  int bh = l >> 6;
  int b = bh >> 4, h = bh & 15;
  int q0 = qt * 32;
  int tid = threadIdx.x;
  int lane = tid & 63, wv = tid >> 6;   // wv 0..7
  int lm = lane & 15, lg = lane >> 4;

  // B-operand frags for Qw only (pre-scaled by log2(e)/8 in GEMM):
  // B[n=lane&15][k=(lane>>4)*8+j]; 2 q-halves x 2 k-halves
  short8 bqw[2][2];
  const size_t qbase = (size_t)(b * S_ + q0) * HD_ + h * 64;
#pragma unroll
  for (int t = 0; t < 2; t++) {
    const unsigned short* p1 = qw + qbase + (size_t)(t * 16 + lm) * HD_ + lg * 8;
    bqw[t][0] = *(const short8*)(p1);
    bqw[t][1] = *(const short8*)(p1 + 32);
  }

  floatx4 acc[2][4];                    // O accumulator (wave's k-share, all q,dh)
#pragma unroll
  for (int m = 0; m < 2; m++)
#pragma unroll
    for (int j = 0; j < 4; j++) acc[m][j] = (floatx4){0.f, 0.f, 0.f, 0.f};
  float s0 = 0.f, s1 = 0.f;             // exp-sum accumulators (t=0/1)

  const unsigned short* vb0 = vt + (size_t)(b * H_ + h) * 64 * S_;
  const float* drph = drp + h * 2048;

  for (int c = 0; c < 4; c++) {
    int kc = c * KC_;
    // ---- A(c): R scatter. j-window [kc-q0-32, kc-q0+511], 34 tiles of 16 ----
    for (int jt = wv; jt < 34; jt += 8) {
      int jb = kc - q0 - 32 + jt * 16;
      int jrow = (jb + lm) & 2047;
      const unsigned short* rp = rb + (size_t)jrow * HD_ + h * 64 + lg * 8;
      short8 a0 = *(const short8*)(rp);
      short8 a1 = *(const short8*)(rp + 32);
      int dj = (jb + lg * 4) & 2047;    // quad never crosses wrap (dj mult of 4)
      floatx4 dv = *(const floatx4*)&drph[dj];
#pragma unroll
      for (int t = 0; t < 2; t++) {
        floatx4 c4 = (floatx4){0.f, 0.f, 0.f, 0.f};
        c4 = __builtin_amdgcn_mfma_f32_16x16x32_bf16(a0, bqw[t][0], c4, 0, 0, 0);
        c4 = __builtin_amdgcn_mfma_f32_16x16x32_bf16(a1, bqw[t][1], c4, 0, 0, 0);
        int q = t * 16 + lm;
        int ub = jt * 16 + lg * 4 + q - 31;   // u = k - kc for this lane's rows
        unsigned short* row = &sS[q * SP2];
        if (jt + t >= 2 && jt + t <= 32) {    // wave-uniform: all 64 lanes in-range
#pragma unroll
          for (int r = 0; r < 4; r++) row[ub + r] = f2h(c4[r] + dv[r]);
        } else {
#pragma unroll
          for (int r = 0; r < 4; r++) {
            int u = ub + r;
            if ((unsigned)u < (unsigned)KC_) row[u] = f2h(c4[r] + dv[r]);
          }
        }
      }
    }
    __syncthreads();                    // A writes visible to all waves
    // ---- B'(c): content + R + exp2 + sum + write P (bf16 via cvt_pk) ----
#pragma unroll 2
    for (int kt = 0; kt < 4; kt++) {
      int u0 = wv * 64 + kt * 16;
      const unsigned short* kp = kb + (size_t)(b * S_ + kc + u0 + lm) * HD_ + h * 64 + lg * 8;
      short8 a0 = *(const short8*)(kp);
      short8 a1 = *(const short8*)(kp + 32);
#pragma unroll
      for (int t = 0; t < 2; t++) {
        floatx4 c4 = (floatx4){0.f, 0.f, 0.f, 0.f};
        c4 = __builtin_amdgcn_mfma_f32_16x16x32_bf16(a0, bqw[t][0], c4, 0, 0, 0);
        c4 = __builtin_amdgcn_mfma_f32_16x16x32_bf16(a1, bqw[t][1], c4, 0, 0, 0);
        int q = t * 16 + lm;
        unsigned short* pp = &sS[q * SP2 + u0 + lg * 4];
        ushort4 Rv = *(const ushort4*)pp;
        float p0 = exp2f(c4[0] + h2f(Rv.x));
        float p1 = exp2f(c4[1] + h2f(Rv.y));
        float p2 = exp2f(c4[2] + h2f(Rv.z));
        float p3 = exp2f(c4[3] + h2f(Rv.w));
        float ps = (p0 + p1) + (p2 + p3);
        if (t == 0) s0 += ps; else s1 += ps;
        unsigned w0, w1;
        asm("v_cvt_pk_bf16_f32 %0, %1, %2" : "=v"(w0) : "v"(p0), "v"(p1));
        asm("v_cvt_pk_bf16_f32 %0, %1, %2" : "=v"(w1) : "v"(p2), "v"(p3));
        *(uint2*)pp = make_uint2(w0, w1);
      }
    }
    // ---- D(c): O += P V (own-wave P columns; same-wave program order).
    //      P reads as 2x b64: dw-stride 258 = 2 mod 32 -> uniform banks. ----
#pragma unroll
    for (int s = 0; s < 2; s++) {
      int u0 = wv * 64 + s * 32;
      int e0 = lm * SP2 + u0 + lg * 8;
      int e1 = (16 + lm) * SP2 + u0 + lg * 8;
      uint2 x0 = *(const uint2*)&sS[e0];
      uint2 x1 = *(const uint2*)&sS[e0 + 4];
      uint2 y0 = *(const uint2*)&sS[e1];
      uint2 y1 = *(const uint2*)&sS[e1 + 4];
      uintx4 ua = {x0.x, x0.y, x1.x, x1.y};
      uintx4 ub = {y0.x, y0.y, y1.x, y1.y};
      short8 a0 = __builtin_bit_cast(short8, ua);
      short8 a1 = __builtin_bit_cast(short8, ub);
      const unsigned short* vp = vb0 + kc + u0 + lg * 8;
#pragma unroll
      for (int j = 0; j < 4; j++) {
        short8 bb = *(const short8*)&vp[(size_t)(j * 16 + lm) * S_];
        acc[0][j] = __builtin_amdgcn_mfma_f32_16x16x32_bf16(a0, bb, acc[0][j], 0, 0, 0);
        acc[1][j] = __builtin_amdgcn_mfma_f32_16x16x32_bf16(a1, bb, acc[1][j], 0, 0, 0);
      }
    }
    __syncthreads();                    // all D reads done before next A writes
  }
  // ---- tail: exp-sum reduce + two-pass O reduce in the single buffer ----
  s0 += __shfl_xor(s0, 16); s0 += __shfl_xor(s0, 32);
  s1 += __shfl_xor(s1, 16); s1 += __shfl_xor(s1, 32);
  if (lane < 16) { sSum[wv][lane] = s0; sSum[wv][16 + lane] = s1; }
  float* po = (float*)sS;               // 4 x 2048 f32 = 32 KiB (fits 33 KB buf)
  if (wv < 4) {
#pragma unroll
    for (int m = 0; m < 2; m++)
#pragma unroll
      for (int j = 0; j < 4; j++)
#pragma unroll
        for (int r = 0; r < 4; r++) {
          int q = m * 16 + lg * 4 + r;
          int dh = j * 16 + lm;
          po[wv * 2048 + q * 64 + dh] = acc[m][j][r];
        }
  }
  __syncthreads();
  if (tid < 32) {
    float t = 0.f;
#pragma unroll
    for (int w = 0; w < 8; w++) t += sSum[w][tid];
    sLinv[tid] = 1.f / t;
  }
  if (wv >= 4) {
#pragma unroll
    for (int m = 0; m < 2; m++)
#pragma unroll
      for (int j = 0; j < 4; j++)
#pragma unroll
        for (int r = 0; r < 4; r++) {
          int q = m * 16 + lg * 4 + r;
          int dh = j * 16 + lm;
          po[(wv - 4) * 2048 + q * 64 + dh] += acc[m][j][r];
        }
  }
  __syncthreads();
  {
    int e = tid * 4;                    // 512 threads x 4 = 2048 outputs
    int q = e >> 6, dh = e & 63;
    float4 v = *(float4*)&po[e];
#pragma unroll
    for (int i = 1; i < 4; i++) {
      float4 u = *(float4*)&po[i * 2048 + e];
      v.x += u.x; v.y += u.y; v.z += u.z; v.w += u.w;
    }
    float li = sLinv[q];
    ushort4 o = make_ushort4(f2bf(v.x * li), f2bf(v.y * li), f2bf(v.z * li), f2bf(v.w * li));
    *(ushort4*)&xb[(size_t)(b * S_ + q0 + q) * HD_ + h * 64 + dh] = o;
  }
}

extern "C" void kernel_launch(void* const* d_in, const int* in_sizes, int n_in,
                              void* d_out, int out_size, void* d_ws, size_t ws_size,
                              hipStream_t stream) {
  const float* inputs_q  = (const float*)d_in[0];
  const float* inputs_kv = (const float*)d_in[1];
  const float* pos_embed = (const float*)d_in[2];
  const float* Wq   = (const float*)d_in[3];
  const float* bq   = (const float*)d_in[4];
  const float* Wk   = (const float*)d_in[5];
  const float* bk   = (const float*)d_in[6];
  const float* Wv   = (const float*)d_in[7];
  const float* bv   = (const float*)d_in[8];
  const float* Wpos = (const float*)d_in[9];
  const float* rrb  = (const float*)d_in[10];
  const float* rwb  = (const float*)d_in[11];
  const float* Wout = (const float*)d_in[12];
  const float* bout = (const float*)d_in[13];
  float* out = (float*)d_out;

  char* ws = (char*)d_ws;                       // ~62 MB used
  unsigned short* aq  = (unsigned short*)(ws);                 // 8MB (reused as xb)
  unsigned short* akv = (unsigned short*)(ws + ( 8u << 20));   // 8MB
  unsigned short* apo = (unsigned short*)(ws + (16u << 20));   // 4MB
  unsigned short* wqt = (unsigned short*)(ws + (20u << 20));   // 2MB each
  unsigned short* wkt = (unsigned short*)(ws + (22u << 20));
  unsigned short* wvt = (unsigned short*)(ws + (24u << 20));
  unsigned short* wpt = (unsigned short*)(ws + (26u << 20));
  unsigned short* wot = (unsigned short*)(ws + (28u << 20));
  unsigned short* qwp = (unsigned short*)(ws + (30u << 20));   // 8MB
  float*          drp = (float*)(ws + (38u << 20));            // 128KB (qr slot freed)
  unsigned short* kbp = (unsigned short*)(ws + (46u << 20));   // 8MB
  unsigned short* vtp = (unsigned short*)(ws + (54u << 20));   // 8MB (vt layout)
  unsigned short* rbp = (unsigned short*)(ws + (62u << 20));   // 4MB
  unsigned short* xbp = aq;                                    // aq dead after q-GEMM

  PrepP pp;
  pp.sq = inputs_q; pp.skv = inputs_kv; pp.spos = pos_embed;
  pp.dq = aq; pp.dkv = akv; pp.dpos = apo;
  pp.ts[0] = Wq; pp.ts[1] = Wk; pp.ts[2] = Wv; pp.ts[3] = Wpos; pp.ts[4] = Wout;
  pp.td[0] = wqt; pp.td[1] = wkt; pp.td[2] = wvt; pp.td[3] = wpt; pp.td[4] = wot;
  prep_all<<<CAST_BLKS + 5120, 256, 0, stream>>>(pp);

  // all 4 projection GEMMs in ONE 896-block launch:
  //   [0,256): q mode1 -> qwp                 [256,384): rpos mode0 -> rbp
  //   [384,640): k mode0 -> kbp               [640,896): v mode4 -> vtp
  GP gp{};
  gp.s[0] = {aq,  wqt, bq,      rwb,     qwp,     nullptr, 1, 256};
  gp.s[1] = {apo, wpt, nullptr, nullptr, rbp,     nullptr, 0, 384};
  gp.s[2] = {akv, wkt, bk,      nullptr, kbp,     nullptr, 0, 640};
  gp.s[3] = {akv, wvt, bv,      nullptr, vtp,     nullptr, 4, 896};
  gemm_bt<<<896, 256, 0, stream>>>(gp, HD_, D_);

  drp_kernel<<<128, 256, 0, stream>>>(rbp, rrb, rwb, drp);

  attn_kernel<<<2048, 512, 0, stream>>>(qwp, kbp, rbp, vtp, drp, xbp);

  GP go{};
  go.s[0] = {xbp, wot, bout, nullptr, nullptr, out, 2, 256};
  go.s[1] = {nullptr, nullptr, nullptr, nullptr, nullptr, nullptr, 0, 1 << 30};
  go.s[2] = go.s[1];
  go.s[3] = go.s[1];
  gemm_bt<<<256, 256, 0, stream>>>(go, F_, HD_);
}

// Round 9
// 448.401 us; speedup vs baseline: 1.1496x; 1.1496x over previous
//
#include <hip/hip_runtime.h>
#include <hip/hip_bf16.h>
#include <hip/hip_fp16.h>

// RelMultiHeadDotProductAttention (Transformer-XL rel attention)
// B=2 S=2048 D=1024 H=16 Dh=64 F=1024. fp32 in/out; internal bf16 MFMA.
// Round 15: occupancy via WORKGROUP GRANULARITY. Register-file model fitted
// to R9-R14: waves/SIMD = floor(512/total_regs); this body = 96 regs (64 VGPR
// + 32 AGPR) -> 5 waves/SIMD; an 8-wave WG floors that to 2 WG (50%) — the
// granularity, not LDS, was the cap. Fix: 256-thread blocks (4 waves),
// KC=256 chunks, wave wv owns cols [wv*64,wv*64+64) — identical per-k-column
// work, natural allocation untouched -> 5 WG/CU = 62.5%. (256,5) caps at 102
// >= 96: no spill (R10/R11/R12/R14 all died forcing regs BELOW natural use).
// drp kept (verified in R14): rel-score = (q+rw).rpos + drp[h][j], kills Qr.
// Spill tripwire: attn WRITE_SIZE must stay ~8.2 MB.

#define B_  2
#define S_  2048
#define D_  1024
#define H_  16
#define DH_ 64
#define HD_ 1024
#define F_  1024
#define N_  4096   // B*S
#define KC_ 256    // k-chunk
#define NCH 8      // chunks
#define SP2 260    // chunk row stride (fp16): 130 dw = 2 mod 32 banks
#define KQSC 0.1803368801111204f  // log2(e)/8, folded into qw (and drp)

typedef __attribute__((ext_vector_type(8))) short  short8;   // 8 x bf16 (4 VGPRs)
typedef __attribute__((ext_vector_type(4))) float  floatx4;
typedef __attribute__((ext_vector_type(4))) unsigned int uintx4;

__device__ __forceinline__ unsigned short f2bf(float x) {
  unsigned u = __float_as_uint(x);
  u += 0x7FFFu + ((u >> 16) & 1u);          // RNE
  return (unsigned short)(u >> 16);
}
__device__ __forceinline__ unsigned short f2h(float x) {
  __half h = __float2half(x);
  unsigned short u; __builtin_memcpy(&u, &h, 2);
  return u;
}
__device__ __forceinline__ float h2f(unsigned short u) {
  __half h; __builtin_memcpy(&h, &u, 2);
  return __half2float(h);
}
__device__ __forceinline__ float bf2f(unsigned short u) {
  return __uint_as_float(((unsigned)u) << 16);
}

// async global->LDS, 16B per lane (dest must be linear base + lane*16)
__device__ __forceinline__ void gld_lds16(const void* g, void* l) {
  __builtin_amdgcn_global_load_lds(
      (const __attribute__((address_space(1))) unsigned int*)g,
      (__attribute__((address_space(3))) unsigned int*)l, 16, 0, 0);
}

// ------- prep: fp32->bf16 casts (q, kv, pos) + 5 weight transposes, ONE launch -------
#define CQ_ (N_ * D_ / 4)   // 1048576 float4 units each for q, kv
#define CAST_BLKS 10240     // (2*CQ_ + S_*D_/4) / 256
struct PrepP {
  const float* sq; const float* skv; const float* spos;
  unsigned short* dq; unsigned short* dkv; unsigned short* dpos;
  const float* ts[5]; unsigned short* td[5];
};
__global__ void prep_all(PrepP p) {
  __shared__ float t[32][33];
  int bid = blockIdx.x;
  int tid = threadIdx.x;
  if (bid < CAST_BLKS) {
    int i = bid * 256 + tid;
    const float* s; unsigned short* d; int off;
    if (i < CQ_)            { s = p.sq;   d = p.dq;   off = i; }
    else if (i < 2 * CQ_)   { s = p.skv;  d = p.dkv;  off = i - CQ_; }
    else                    { s = p.spos; d = p.dpos; off = i - 2 * CQ_; }
    float4 v = ((const float4*)s)[off];
    ((ushort4*)d)[off] = make_ushort4(f2bf(v.x), f2bf(v.y), f2bf(v.z), f2bf(v.w));
  } else {
    int b2 = bid - CAST_BLKS;               // 0..5119: 5 matrices x 32x32 tiles
    int z = b2 >> 10, y = (b2 >> 5) & 31, x = b2 & 31;
    const float* src = p.ts[z];
    unsigned short* dst = p.td[z];
    int c0 = x * 32, r0 = y * 32;
    int tx = tid & 31, ty = tid >> 5;       // (32,8)
#pragma unroll
    for (int i = 0; i < 4; i++)
      t[ty + i * 8][tx] = src[(size_t)(r0 + ty + i * 8) * 1024 + c0 + tx];
    __syncthreads();
#pragma unroll
    for (int i = 0; i < 4; i++)
      dst[(size_t)(c0 + ty + i * 8) * 1024 + r0 + tx] = f2bf(t[tx][ty + i * 8]);
  }
}

// ------- drp[h][j] = KQSC * sum_k (rrb-rwb)[h][k] * rpos[j][h][k] -------
// 32768 threads: one (j,h) each; rbp is bf16 [j][h][k].  [verified R14]
__global__ void drp_kernel(const unsigned short* __restrict__ rbp,
                           const float* __restrict__ rrb, const float* __restrict__ rwb,
                           float* __restrict__ drp) {
  int idx = blockIdx.x * 256 + threadIdx.x;
  int j = idx >> 4, h = idx & 15;
  const unsigned short* rp = rbp + (size_t)j * HD_ + h * 64;
  const float* pa = rrb + h * 64;
  const float* pb = rwb + h * 64;
  float s = 0.f;
#pragma unroll
  for (int k = 0; k < 64; k += 8) {
    short8 v = *(const short8*)(rp + k);
#pragma unroll
    for (int e = 0; e < 8; e++)
      s += (pa[k + e] - pb[k + e]) * bf2f((unsigned short)v[e]);
  }
  drp[h * 2048 + j] = s * KQSC;
}

// ---------------- bf16 GEMM, C = A[M][K] * Bt[N][K]^T + bias ----------------
// 4-segment dispatch: block bx picks segment by bend boundaries (monotone).
// mode 0: outA bf16 = acc + bias
// mode 1: outA bf16 = (acc+bias+b2a)*KQSC
// mode 2: outF fp32 = acc + bias
// mode 4: bf16, written directly in vt layout [b][h][dh][s]
// Staging via global_load_lds width=16 (dest linear: elem off = tid*8 = tid*16B).
struct GSeg {
  const unsigned short* A; const unsigned short* Bt;
  const float* bias; const float* b2a;
  unsigned short* outA; float* outF;
  int mode; int bend;
};
struct GP { GSeg s[4]; };
__launch_bounds__(256, 2)
__global__ void gemm_bt(GP p, int Nn, int K) {
  __shared__ unsigned short As[128 * 64];
  __shared__ unsigned short Bs[128 * 64];
  int bx = blockIdx.x;
  GSeg g = p.s[0]; int base = 0;
  if (bx >= p.s[0].bend) { g = p.s[1]; base = p.s[0].bend; }
  if (bx >= p.s[1].bend) { g = p.s[2]; base = p.s[1].bend; }
  if (bx >= p.s[2].bend) { g = p.s[3]; base = p.s[2].bend; }
  bx -= base;
  int nb = Nn >> 7;
  int bm = bx / nb, bn = bx % nb;
  int tid = threadIdx.x;
  int lane = tid & 63, wv = tid >> 6;
  int wm = wv >> 1, wn = wv & 1;
  int lm = lane & 15, lg = lane >> 4;
  const unsigned short* Ab = g.A + (size_t)(bm * 128) * K;
  const unsigned short* Bb = g.Bt + (size_t)(bn * 128) * K;
  floatx4 acc[4][4];
#pragma unroll
  for (int i = 0; i < 4; i++)
#pragma unroll
    for (int j = 0; j < 4; j++) acc[i][j] = (floatx4){0.f, 0.f, 0.f, 0.f};

  int lr = tid >> 3;          // 0..31 staging row
  int lc = (tid & 7) * 8;     // staging col (8 bf16 = 16B)
  for (int k0 = 0; k0 < K; k0 += 64) {
    __syncthreads();
#pragma unroll
    for (int i = 0; i < 4; i++) {
      int r = i * 32 + lr;
      gld_lds16(&Ab[(size_t)r * K + k0 + lc], &As[r * 64 + lc]);
      gld_lds16(&Bb[(size_t)r * K + k0 + lc], &Bs[r * 64 + lc]);
    }
    __syncthreads();
#pragma unroll
    for (int kk = 0; kk < 2; kk++) {
      short8 af[4], bf[4];
#pragma unroll
      for (int i = 0; i < 4; i++)
        af[i] = *(const short8*)&As[(wm * 64 + i * 16 + lm) * 64 + kk * 32 + lg * 8];
#pragma unroll
      for (int j = 0; j < 4; j++)
        bf[j] = *(const short8*)&Bs[(wn * 64 + j * 16 + lm) * 64 + kk * 32 + lg * 8];
#pragma unroll
      for (int i = 0; i < 4; i++)
#pragma unroll
        for (int j = 0; j < 4; j++)
          acc[i][j] = __builtin_amdgcn_mfma_f32_16x16x32_bf16(af[i], bf[j], acc[i][j], 0, 0, 0);
    }
  }
  // epilogue: C/D layout col=lane&15, row=(lane>>4)*4+reg  [m89/m91 verified]
#pragma unroll
  for (int j = 0; j < 4; j++) {
    int col = bn * 128 + wn * 64 + j * 16 + lm;
    float bs = g.bias ? g.bias[col] : 0.f;
    float ba = g.b2a ? g.b2a[col] : 0.f;
#pragma unroll
    for (int i = 0; i < 4; i++) {
      int row0 = bm * 128 + wm * 64 + i * 16 + lg * 4;
      if (g.mode == 4) {
        // vt[b][h][dh][s]: 4 consecutive s -> vector store
        int s = row0 & 2047, bb2 = row0 >> 11;
        size_t vidx = (((size_t)bb2 * H_ + (col >> 6)) * 64 + (col & 63)) * (size_t)S_ + s;
        ushort4 o = make_ushort4(f2bf(acc[i][j][0] + bs), f2bf(acc[i][j][1] + bs),
                                 f2bf(acc[i][j][2] + bs), f2bf(acc[i][j][3] + bs));
        *(ushort4*)&g.outA[vidx] = o;
      } else {
#pragma unroll
        for (int r = 0; r < 4; r++) {
          float v = acc[i][j][r] + bs;
          size_t idx = (size_t)(row0 + r) * Nn + col;
          if (g.mode == 0)      g.outA[idx] = f2bf(v);
          else if (g.mode == 1) g.outA[idx] = f2bf((v + ba) * KQSC);
          else                  g.outF[idx] = v;
        }
      }
    }
  }
}

// ---------------- fused rel-attention per (b, h, 32-query tile) ----------------
// 256 threads = 4 waves, ~17.3 KiB LDS. Wave wv owns k-cols
// [wv*64, wv*64+64) of each 256-chunk (8 chunks) — same per-k-column work as
// the 512-thread version; finer WG granularity -> 5 WG/CU at 96 regs.
//   A(c): rpos.Qw^T MFMA + drp[h][j], scatter fp16 into score buffer
//   barrier; B'(c): K.Qw^T + R + exp2 + sum (regs), P bf16 in place (cvt_pk)
//   D(c): O += P V (own-wave P cols, same-wave program order, no barrier)
//   barrier (all D reads done before next chunk's A overwrites the buffer)
// Tail: cross-wave sum reduce; two-pass 4->2->1 O reduce (po[2][2048] fits).
__launch_bounds__(256, 5)
__global__ void attn_kernel(const unsigned short* __restrict__ qw,
                            const unsigned short* __restrict__ kb,
                            const unsigned short* __restrict__ rb,
                            const unsigned short* __restrict__ vt,
                            const float* __restrict__ drp,
                            unsigned short* __restrict__ xb) {
  __shared__ __align__(16) unsigned short sS[32 * SP2];  // score chunk (16.6 KB)
  __shared__ float sSum[4][32];
  __shared__ float sLinv[32];
  int bid = blockIdx.x;                 // 2048 = 32 bh * 64 qt
  int l = ((bid & 7) << 8) | (bid >> 3);  // XCD swizzle: xcd gets 4 whole bh
  int qt = l & 63;
  int bh = l >> 6;
  int b = bh >> 4, h = bh & 15;
  int q0 = qt * 32;
  int tid = threadIdx.x;
  int lane = tid & 63, wv = tid >> 6;   // wv 0..3
  int lm = lane & 15, lg = lane >> 4;

  // B-operand frags for Qw only (pre-scaled by log2(e)/8 in GEMM):
  // B[n=lane&15][k=(lane>>4)*8+j]; 2 q-halves x 2 k-halves
  short8 bqw[2][2];
  const size_t qbase = (size_t)(b * S_ + q0) * HD_ + h * 64;
#pragma unroll
  for (int t = 0; t < 2; t++) {
    const unsigned short* p1 = qw + qbase + (size_t)(t * 16 + lm) * HD_ + lg * 8;
    bqw[t][0] = *(const short8*)(p1);
    bqw[t][1] = *(const short8*)(p1 + 32);
  }

  floatx4 acc[2][4];                    // O accumulator (wave's k-share, all q,dh)
#pragma unroll
  for (int m = 0; m < 2; m++)
#pragma unroll
    for (int j = 0; j < 4; j++) acc[m][j] = (floatx4){0.f, 0.f, 0.f, 0.f};
  float s0 = 0.f, s1 = 0.f;             // exp-sum accumulators (t=0/1)

  const unsigned short* vb0 = vt + (size_t)(b * H_ + h) * 64 * S_;
  const float* drph = drp + h * 2048;

  for (int c = 0; c < NCH; c++) {
    int kc = c * KC_;
    // ---- A(c): R scatter. j-window [kc-q0-32, kc-q0+255], 18 tiles of 16 ----
    for (int jt = wv; jt < 18; jt += 4) {
      int jb = kc - q0 - 32 + jt * 16;
      int jrow = (jb + lm) & 2047;
      const unsigned short* rp = rb + (size_t)jrow * HD_ + h * 64 + lg * 8;
      short8 a0 = *(const short8*)(rp);
      short8 a1 = *(const short8*)(rp + 32);
      int dj = (jb + lg * 4) & 2047;    // quad never crosses wrap (dj mult of 4)
      floatx4 dv = *(const floatx4*)&drph[dj];
#pragma unroll
      for (int t = 0; t < 2; t++) {
        floatx4 c4 = (floatx4){0.f, 0.f, 0.f, 0.f};
        c4 = __builtin_amdgcn_mfma_f32_16x16x32_bf16(a0, bqw[t][0], c4, 0, 0, 0);
        c4 = __builtin_amdgcn_mfma_f32_16x16x32_bf16(a1, bqw[t][1], c4, 0, 0, 0);
        int q = t * 16 + lm;
        int ub = jt * 16 + lg * 4 + q - 31;   // u = k - kc for this lane's rows
        unsigned short* row = &sS[q * SP2];
        if (jt + t >= 2 && jt + t <= 16) {    // wave-uniform: all 64 lanes in-range
#pragma unroll
          for (int r = 0; r < 4; r++) row[ub + r] = f2h(c4[r] + dv[r]);
        } else {
#pragma unroll
          for (int r = 0; r < 4; r++) {
            int u = ub + r;
            if ((unsigned)u < (unsigned)KC_) row[u] = f2h(c4[r] + dv[r]);
          }
        }
      }
    }
    __syncthreads();                    // A writes visible to all waves
    // ---- B'(c): content + R + exp2 + sum + write P (bf16 via cvt_pk) ----
#pragma unroll 2
    for (int kt = 0; kt < 4; kt++) {
      int u0 = wv * 64 + kt * 16;
      const unsigned short* kp = kb + (size_t)(b * S_ + kc + u0 + lm) * HD_ + h * 64 + lg * 8;
      short8 a0 = *(const short8*)(kp);
      short8 a1 = *(const short8*)(kp + 32);
#pragma unroll
      for (int t = 0; t < 2; t++) {
        floatx4 c4 = (floatx4){0.f, 0.f, 0.f, 0.f};
        c4 = __builtin_amdgcn_mfma_f32_16x16x32_bf16(a0, bqw[t][0], c4, 0, 0, 0);
        c4 = __builtin_amdgcn_mfma_f32_16x16x32_bf16(a1, bqw[t][1], c4, 0, 0, 0);
        int q = t * 16 + lm;
        unsigned short* pp = &sS[q * SP2 + u0 + lg * 4];
        ushort4 Rv = *(const ushort4*)pp;
        float p0 = exp2f(c4[0] + h2f(Rv.x));
        float p1 = exp2f(c4[1] + h2f(Rv.y));
        float p2 = exp2f(c4[2] + h2f(Rv.z));
        float p3 = exp2f(c4[3] + h2f(Rv.w));
        float ps = (p0 + p1) + (p2 + p3);
        if (t == 0) s0 += ps; else s1 += ps;
        unsigned w0, w1;
        asm("v_cvt_pk_bf16_f32 %0, %1, %2" : "=v"(w0) : "v"(p0), "v"(p1));
        asm("v_cvt_pk_bf16_f32 %0, %1, %2" : "=v"(w1) : "v"(p2), "v"(p3));
        *(uint2*)pp = make_uint2(w0, w1);
      }
    }
    // ---- D(c): O += P V (own-wave P columns; same-wave program order).
    //      P reads as 2x b64: dw-stride 130 = 2 mod 32 -> uniform banks. ----
#pragma unroll
    for (int s = 0; s < 2; s++) {
      int u0 = wv * 64 + s * 32;
      int e0 = lm * SP2 + u0 + lg * 8;
      int e1 = (16 + lm) * SP2 + u0 + lg * 8;
      uint2 x0 = *(const uint2*)&sS[e0];
      uint2 x1 = *(const uint2*)&sS[e0 + 4];
      uint2 y0 = *(const uint2*)&sS[e1];
      uint2 y1 = *(const uint2*)&sS[e1 + 4];
      uintx4 ua = {x0.x, x0.y, x1.x, x1.y};
      uintx4 ub = {y0.x, y0.y, y1.x, y1.y};
      short8 a0 = __builtin_bit_cast(short8, ua);
      short8 a1 = __builtin_bit_cast(short8, ub);
      const unsigned short* vp = vb0 + kc + u0 + lg * 8;
#pragma unroll
      for (int j = 0; j < 4; j++) {
        short8 bb = *(const short8*)&vp[(size_t)(j * 16 + lm) * S_];
        acc[0][j] = __builtin_amdgcn_mfma_f32_16x16x32_bf16(a0, bb, acc[0][j], 0, 0, 0);
        acc[1][j] = __builtin_amdgcn_mfma_f32_16x16x32_bf16(a1, bb, acc[1][j], 0, 0, 0);
      }
    }
    __syncthreads();                    // all D reads done before next A writes
  }
  // ---- tail: exp-sum reduce + two-pass O reduce (po[2][2048] = 16 KB) ----
  s0 += __shfl_xor(s0, 16); s0 += __shfl_xor(s0, 32);
  s1 += __shfl_xor(s1, 16); s1 += __shfl_xor(s1, 32);
  if (lane < 16) { sSum[wv][lane] = s0; sSum[wv][16 + lane] = s1; }
  float* po = (float*)sS;
  if (wv < 2) {
#pragma unroll
    for (int m = 0; m < 2; m++)
#pragma unroll
      for (int j = 0; j < 4; j++)
#pragma unroll
        for (int r = 0; r < 4; r++) {
          int q = m * 16 + lg * 4 + r;
          int dh = j * 16 + lm;
          po[wv * 2048 + q * 64 + dh] = acc[m][j][r];
        }
  }
  __syncthreads();
  if (tid < 32) {
    float t = 0.f;
#pragma unroll
    for (int w = 0; w < 4; w++) t += sSum[w][tid];
    sLinv[tid] = 1.f / t;
  }
  if (wv >= 2) {
#pragma unroll
    for (int m = 0; m < 2; m++)
#pragma unroll
      for (int j = 0; j < 4; j++)
#pragma unroll
        for (int r = 0; r < 4; r++) {
          int q = m * 16 + lg * 4 + r;
          int dh = j * 16 + lm;
          po[(wv - 2) * 2048 + q * 64 + dh] += acc[m][j][r];
        }
  }
  __syncthreads();
  {
    int e = tid * 8;                    // 256 threads x 8 = 2048 outputs
    int q = e >> 6, dh = e & 63;
    float4 v0 = *(float4*)&po[e];
    float4 v1 = *(float4*)&po[e + 4];
    float4 u0 = *(float4*)&po[2048 + e];
    float4 u1 = *(float4*)&po[2048 + e + 4];
    v0.x += u0.x; v0.y += u0.y; v0.z += u0.z; v0.w += u0.w;
    v1.x += u1.x; v1.y += u1.y; v1.z += u1.z; v1.w += u1.w;
    float li = sLinv[q];
    unsigned short* op = &xb[(size_t)(b * S_ + q0 + q) * HD_ + h * 64 + dh];
    *(ushort4*)op = make_ushort4(f2bf(v0.x * li), f2bf(v0.y * li),
                                 f2bf(v0.z * li), f2bf(v0.w * li));
    *(ushort4*)(op + 4) = make_ushort4(f2bf(v1.x * li), f2bf(v1.y * li),
                                       f2bf(v1.z * li), f2bf(v1.w * li));
  }
}

extern "C" void kernel_launch(void* const* d_in, const int* in_sizes, int n_in,
                              void* d_out, int out_size, void* d_ws, size_t ws_size,
                              hipStream_t stream) {
  const float* inputs_q  = (const float*)d_in[0];
  const float* inputs_kv = (const float*)d_in[1];
  const float* pos_embed = (const float*)d_in[2];
  const float* Wq   = (const float*)d_in[3];
  const float* bq   = (const float*)d_in[4];
  const float* Wk   = (const float*)d_in[5];
  const float* bk   = (const float*)d_in[6];
  const float* Wv   = (const float*)d_in[7];
  const float* bv   = (const float*)d_in[8];
  const float* Wpos = (const float*)d_in[9];
  const float* rrb  = (const float*)d_in[10];
  const float* rwb  = (const float*)d_in[11];
  const float* Wout = (const float*)d_in[12];
  const float* bout = (const float*)d_in[13];
  float* out = (float*)d_out;

  char* ws = (char*)d_ws;                       // ~62 MB used
  unsigned short* aq  = (unsigned short*)(ws);                 // 8MB (reused as xb)
  unsigned short* akv = (unsigned short*)(ws + ( 8u << 20));   // 8MB
  unsigned short* apo = (unsigned short*)(ws + (16u << 20));   // 4MB
  unsigned short* wqt = (unsigned short*)(ws + (20u << 20));   // 2MB each
  unsigned short* wkt = (unsigned short*)(ws + (22u << 20));
  unsigned short* wvt = (unsigned short*)(ws + (24u << 20));
  unsigned short* wpt = (unsigned short*)(ws + (26u << 20));
  unsigned short* wot = (unsigned short*)(ws + (28u << 20));
  unsigned short* qwp = (unsigned short*)(ws + (30u << 20));   // 8MB
  float*          drp = (float*)(ws + (38u << 20));            // 128KB
  unsigned short* kbp = (unsigned short*)(ws + (46u << 20));   // 8MB
  unsigned short* vtp = (unsigned short*)(ws + (54u << 20));   // 8MB (vt layout)
  unsigned short* rbp = (unsigned short*)(ws + (62u << 20));   // 4MB
  unsigned short* xbp = aq;                                    // aq dead after q-GEMM

  PrepP pp;
  pp.sq = inputs_q; pp.skv = inputs_kv; pp.spos = pos_embed;
  pp.dq = aq; pp.dkv = akv; pp.dpos = apo;
  pp.ts[0] = Wq; pp.ts[1] = Wk; pp.ts[2] = Wv; pp.ts[3] = Wpos; pp.ts[4] = Wout;
  pp.td[0] = wqt; pp.td[1] = wkt; pp.td[2] = wvt; pp.td[3] = wpt; pp.td[4] = wot;
  prep_all<<<CAST_BLKS + 5120, 256, 0, stream>>>(pp);

  // all 4 projection GEMMs in ONE 896-block launch:
  //   [0,256): q mode1 -> qwp                 [256,384): rpos mode0 -> rbp
  //   [384,640): k mode0 -> kbp               [640,896): v mode4 -> vtp
  GP gp{};
  gp.s[0] = {aq,  wqt, bq,      rwb,     qwp,     nullptr, 1, 256};
  gp.s[1] = {apo, wpt, nullptr, nullptr, rbp,     nullptr, 0, 384};
  gp.s[2] = {akv, wkt, bk,      nullptr, kbp,     nullptr, 0, 640};
  gp.s[3] = {akv, wvt, bv,      nullptr, vtp,     nullptr, 4, 896};
  gemm_bt<<<896, 256, 0, stream>>>(gp, HD_, D_);

  drp_kernel<<<128, 256, 0, stream>>>(rbp, rrb, rwb, drp);

  attn_kernel<<<2048, 256, 0, stream>>>(qwp, kbp, rbp, vtp, drp, xbp);

  GP go{};
  go.s[0] = {xbp, wot, bout, nullptr, nullptr, out, 2, 256};
  go.s[1] = {nullptr, nullptr, nullptr, nullptr, nullptr, nullptr, 0, 1 << 30};
  go.s[2] = go.s[1];
  go.s[3] = go.s[1];
  gemm_bt<<<256, 256, 0, stream>>>(go, F_, HD_);
}

// Round 10
// 410.077 us; speedup vs baseline: 1.2570x; 1.0935x over previous
//
#include <hip/hip_runtime.h>
#include <hip/hip_bf16.h>
#include <hip/hip_fp16.h>

// RelMultiHeadDotProductAttention (Transformer-XL rel attention)
// B=2 S=2048 D=1024 H=16 Dh=64 F=1024. fp32 in/out; internal bf16 MFMA.
// Round 16: back to the measured-best R9 envelope (8 waves, 66KB dbuf LDS,
// (512,4), 2 WG/CU — every occupancy push R10-R15 lost). Shorten the per-wave
// critical path within it, funded by drp (verified R14/R15):
//   - drp[h][j] replaces bqr: -16 persistent regs, -8MB q-GEMM traffic.
//   - A-phase 1-deep pipeline (R11's rotating named vars): R-load latency
//     hides under previous tile's MFMA+scatter.
//   - B' K-prefetch: kt0 pre-barrier (flies under barrier drain), kt+1
//     issued before computing kt.
// Peak live ~85-90 regs < 128 cap. Spill tripwire: WRITE_SIZE ~8.2 MB.

#define B_  2
#define S_  2048
#define D_  1024
#define H_  16
#define DH_ 64
#define HD_ 1024
#define F_  1024
#define N_  4096   // B*S
#define KC_ 512    // k-chunk
#define SP2 516    // chunk row stride (fp16): 258 dw = 2 mod 32 banks
#define KQSC 0.1803368801111204f  // log2(e)/8, folded into qw (and drp)

typedef __attribute__((ext_vector_type(8))) short  short8;   // 8 x bf16 (4 VGPRs)
typedef __attribute__((ext_vector_type(4))) float  floatx4;
typedef __attribute__((ext_vector_type(4))) unsigned int uintx4;

__device__ __forceinline__ unsigned short f2bf(float x) {
  unsigned u = __float_as_uint(x);
  u += 0x7FFFu + ((u >> 16) & 1u);          // RNE
  return (unsigned short)(u >> 16);
}
__device__ __forceinline__ unsigned short f2h(float x) {
  __half h = __float2half(x);
  unsigned short u; __builtin_memcpy(&u, &h, 2);
  return u;
}
__device__ __forceinline__ float h2f(unsigned short u) {
  __half h; __builtin_memcpy(&h, &u, 2);
  return __half2float(h);
}
__device__ __forceinline__ float bf2f(unsigned short u) {
  return __uint_as_float(((unsigned)u) << 16);
}

// async global->LDS, 16B per lane (dest must be linear base + lane*16)
__device__ __forceinline__ void gld_lds16(const void* g, void* l) {
  __builtin_amdgcn_global_load_lds(
      (const __attribute__((address_space(1))) unsigned int*)g,
      (__attribute__((address_space(3))) unsigned int*)l, 16, 0, 0);
}

// ------- prep: fp32->bf16 casts (q, kv, pos) + 5 weight transposes, ONE launch -------
#define CQ_ (N_ * D_ / 4)   // 1048576 float4 units each for q, kv
#define CAST_BLKS 10240     // (2*CQ_ + S_*D_/4) / 256
struct PrepP {
  const float* sq; const float* skv; const float* spos;
  unsigned short* dq; unsigned short* dkv; unsigned short* dpos;
  const float* ts[5]; unsigned short* td[5];
};
__global__ void prep_all(PrepP p) {
  __shared__ float t[32][33];
  int bid = blockIdx.x;
  int tid = threadIdx.x;
  if (bid < CAST_BLKS) {
    int i = bid * 256 + tid;
    const float* s; unsigned short* d; int off;
    if (i < CQ_)            { s = p.sq;   d = p.dq;   off = i; }
    else if (i < 2 * CQ_)   { s = p.skv;  d = p.dkv;  off = i - CQ_; }
    else                    { s = p.spos; d = p.dpos; off = i - 2 * CQ_; }
    float4 v = ((const float4*)s)[off];
    ((ushort4*)d)[off] = make_ushort4(f2bf(v.x), f2bf(v.y), f2bf(v.z), f2bf(v.w));
  } else {
    int b2 = bid - CAST_BLKS;               // 0..5119: 5 matrices x 32x32 tiles
    int z = b2 >> 10, y = (b2 >> 5) & 31, x = b2 & 31;
    const float* src = p.ts[z];
    unsigned short* dst = p.td[z];
    int c0 = x * 32, r0 = y * 32;
    int tx = tid & 31, ty = tid >> 5;       // (32,8)
#pragma unroll
    for (int i = 0; i < 4; i++)
      t[ty + i * 8][tx] = src[(size_t)(r0 + ty + i * 8) * 1024 + c0 + tx];
    __syncthreads();
#pragma unroll
    for (int i = 0; i < 4; i++)
      dst[(size_t)(c0 + ty + i * 8) * 1024 + r0 + tx] = f2bf(t[tx][ty + i * 8]);
  }
}

// ------- drp[h][j] = KQSC * sum_k (rrb-rwb)[h][k] * rpos[j][h][k] -------
// 32768 threads: one (j,h) each; rbp is bf16 [j][h][k].  [verified R14/R15]
__global__ void drp_kernel(const unsigned short* __restrict__ rbp,
                           const float* __restrict__ rrb, const float* __restrict__ rwb,
                           float* __restrict__ drp) {
  int idx = blockIdx.x * 256 + threadIdx.x;
  int j = idx >> 4, h = idx & 15;
  const unsigned short* rp = rbp + (size_t)j * HD_ + h * 64;
  const float* pa = rrb + h * 64;
  const float* pb = rwb + h * 64;
  float s = 0.f;
#pragma unroll
  for (int k = 0; k < 64; k += 8) {
    short8 v = *(const short8*)(rp + k);
#pragma unroll
    for (int e = 0; e < 8; e++)
      s += (pa[k + e] - pb[k + e]) * bf2f((unsigned short)v[e]);
  }
  drp[h * 2048 + j] = s * KQSC;
}

// ---------------- bf16 GEMM, C = A[M][K] * Bt[N][K]^T + bias ----------------
// 4-segment dispatch: block bx picks segment by bend boundaries (monotone).
// mode 0: outA bf16 = acc + bias
// mode 1: outA bf16 = (acc+bias+b2a)*KQSC
// mode 2: outF fp32 = acc + bias
// mode 4: bf16, written directly in vt layout [b][h][dh][s]
// Staging via global_load_lds width=16 (dest linear: elem off = tid*8 = tid*16B).
struct GSeg {
  const unsigned short* A; const unsigned short* Bt;
  const float* bias; const float* b2a;
  unsigned short* outA; float* outF;
  int mode; int bend;
};
struct GP { GSeg s[4]; };
__launch_bounds__(256, 2)
__global__ void gemm_bt(GP p, int Nn, int K) {
  __shared__ unsigned short As[128 * 64];
  __shared__ unsigned short Bs[128 * 64];
  int bx = blockIdx.x;
  GSeg g = p.s[0]; int base = 0;
  if (bx >= p.s[0].bend) { g = p.s[1]; base = p.s[0].bend; }
  if (bx >= p.s[1].bend) { g = p.s[2]; base = p.s[1].bend; }
  if (bx >= p.s[2].bend) { g = p.s[3]; base = p.s[2].bend; }
  bx -= base;
  int nb = Nn >> 7;
  int bm = bx / nb, bn = bx % nb;
  int tid = threadIdx.x;
  int lane = tid & 63, wv = tid >> 6;
  int wm = wv >> 1, wn = wv & 1;
  int lm = lane & 15, lg = lane >> 4;
  const unsigned short* Ab = g.A + (size_t)(bm * 128) * K;
  const unsigned short* Bb = g.Bt + (size_t)(bn * 128) * K;
  floatx4 acc[4][4];
#pragma unroll
  for (int i = 0; i < 4; i++)
#pragma unroll
    for (int j = 0; j < 4; j++) acc[i][j] = (floatx4){0.f, 0.f, 0.f, 0.f};

  int lr = tid >> 3;          // 0..31 staging row
  int lc = (tid & 7) * 8;     // staging col (8 bf16 = 16B)
  for (int k0 = 0; k0 < K; k0 += 64) {
    __syncthreads();
#pragma unroll
    for (int i = 0; i < 4; i++) {
      int r = i * 32 + lr;
      gld_lds16(&Ab[(size_t)r * K + k0 + lc], &As[r * 64 + lc]);
      gld_lds16(&Bb[(size_t)r * K + k0 + lc], &Bs[r * 64 + lc]);
    }
    __syncthreads();
#pragma unroll
    for (int kk = 0; kk < 2; kk++) {
      short8 af[4], bf[4];
#pragma unroll
      for (int i = 0; i < 4; i++)
        af[i] = *(const short8*)&As[(wm * 64 + i * 16 + lm) * 64 + kk * 32 + lg * 8];
#pragma unroll
      for (int j = 0; j < 4; j++)
        bf[j] = *(const short8*)&Bs[(wn * 64 + j * 16 + lm) * 64 + kk * 32 + lg * 8];
#pragma unroll
      for (int i = 0; i < 4; i++)
#pragma unroll
        for (int j = 0; j < 4; j++)
          acc[i][j] = __builtin_amdgcn_mfma_f32_16x16x32_bf16(af[i], bf[j], acc[i][j], 0, 0, 0);
    }
  }
  // epilogue: C/D layout col=lane&15, row=(lane>>4)*4+reg  [m89/m91 verified]
#pragma unroll
  for (int j = 0; j < 4; j++) {
    int col = bn * 128 + wn * 64 + j * 16 + lm;
    float bs = g.bias ? g.bias[col] : 0.f;
    float ba = g.b2a ? g.b2a[col] : 0.f;
#pragma unroll
    for (int i = 0; i < 4; i++) {
      int row0 = bm * 128 + wm * 64 + i * 16 + lg * 4;
      if (g.mode == 4) {
        // vt[b][h][dh][s]: 4 consecutive s -> vector store
        int s = row0 & 2047, bb2 = row0 >> 11;
        size_t vidx = (((size_t)bb2 * H_ + (col >> 6)) * 64 + (col & 63)) * (size_t)S_ + s;
        ushort4 o = make_ushort4(f2bf(acc[i][j][0] + bs), f2bf(acc[i][j][1] + bs),
                                 f2bf(acc[i][j][2] + bs), f2bf(acc[i][j][3] + bs));
        *(ushort4*)&g.outA[vidx] = o;
      } else {
#pragma unroll
        for (int r = 0; r < 4; r++) {
          float v = acc[i][j][r] + bs;
          size_t idx = (size_t)(row0 + r) * Nn + col;
          if (g.mode == 0)      g.outA[idx] = f2bf(v);
          else if (g.mode == 1) g.outA[idx] = f2bf((v + ba) * KQSC);
          else                  g.outF[idx] = v;
        }
      }
    }
  }
}

// ---------------- fused rel-attention per (b, h, 32-query tile) ----------------
// R9 envelope: 512 threads = 8 waves, 66 KiB dbuf LDS, 2 WG/CU, 4 chunks of
// 512, wave wv owns k-share [wv*64, wv*64+64). ONE barrier per chunk.
//   A(c): R scatter, 1-deep pipelined (load jt+8 + drp quad while computing jt)
//   pre-barrier: kt0 K-frags issued (latency under A tail + barrier drain)
//   B'(c): kt+1 K-frags issued before computing kt; MFMA+R+exp2+cvt_pk P
//   D(c): O += P V (own-wave P cols; dbuf lets D(c) overlap A(c+1))
// Tail: cross-wave sum reduce, 8-way O reduce via reused score LDS.
__launch_bounds__(512, 4)
__global__ void attn_kernel(const unsigned short* __restrict__ qw,
                            const unsigned short* __restrict__ kb,
                            const unsigned short* __restrict__ rb,
                            const unsigned short* __restrict__ vt,
                            const float* __restrict__ drp,
                            unsigned short* __restrict__ xb) {
  __shared__ __align__(16) unsigned short sS[2][32 * SP2];  // dbuf score chunks
  __shared__ float sSum[8][32];
  __shared__ float sLinv[32];
  int bid = blockIdx.x;                 // 2048 = 32 bh * 64 qt
  int l = ((bid & 7) << 8) | (bid >> 3);  // XCD swizzle: xcd gets 4 whole bh
  int qt = l & 63;
  int bh = l >> 6;
  int b = bh >> 4, h = bh & 15;
  int q0 = qt * 32;
  int tid = threadIdx.x;
  int lane = tid & 63, wv = tid >> 6;   // wv 0..7
  int lm = lane & 15, lg = lane >> 4;

  // B-operand frags for Qw only (pre-scaled by log2(e)/8 in GEMM):
  // B[n=lane&15][k=(lane>>4)*8+j]; 2 q-halves x 2 k-halves
  short8 bqw[2][2];
  const size_t qbase = (size_t)(b * S_ + q0) * HD_ + h * 64;
#pragma unroll
  for (int t = 0; t < 2; t++) {
    const unsigned short* p1 = qw + qbase + (size_t)(t * 16 + lm) * HD_ + lg * 8;
    bqw[t][0] = *(const short8*)(p1);
    bqw[t][1] = *(const short8*)(p1 + 32);
  }

  floatx4 acc[2][4];                    // O accumulator (wave's k-share, all q,dh)
#pragma unroll
  for (int m = 0; m < 2; m++)
#pragma unroll
    for (int j = 0; j < 4; j++) acc[m][j] = (floatx4){0.f, 0.f, 0.f, 0.f};
  float s0 = 0.f, s1 = 0.f;             // exp-sum accumulators (t=0/1)

  const unsigned short* vb0 = vt + (size_t)(b * H_ + h) * 64 * S_;
  const float* drph = drp + h * 2048;
  const unsigned short* kw0 = kb + (size_t)(b * S_ + wv * 64 + lm) * HD_ + h * 64 + lg * 8;

  for (int c = 0; c < 4; c++) {
    unsigned short* S = sS[c & 1];
    int kc = c * KC_;

    // ---- A(c): R scatter, 1-deep pipelined over jt = wv, wv+8, ... < 34 ----
    auto rload = [&](int jt, short8& a0, short8& a1, floatx4& dv) {
      int jb = kc - q0 - 32 + jt * 16;
      int jrow = (jb + lm) & 2047;
      const unsigned short* rp = rb + (size_t)jrow * HD_ + h * 64 + lg * 8;
      a0 = *(const short8*)(rp);
      a1 = *(const short8*)(rp + 32);
      dv = *(const floatx4*)&drph[(jb + lg * 4) & 2047];
    };
    auto rstore = [&](int jt, short8 a0, short8 a1, floatx4 dv) {
#pragma unroll
      for (int t = 0; t < 2; t++) {
        floatx4 c4 = (floatx4){0.f, 0.f, 0.f, 0.f};
        c4 = __builtin_amdgcn_mfma_f32_16x16x32_bf16(a0, bqw[t][0], c4, 0, 0, 0);
        c4 = __builtin_amdgcn_mfma_f32_16x16x32_bf16(a1, bqw[t][1], c4, 0, 0, 0);
        int q = t * 16 + lm;
        int ub = jt * 16 + lg * 4 + q - 31;   // u = k - kc for this lane's rows
        unsigned short* row = &S[q * SP2];
        if (jt + t >= 2 && jt + t <= 32) {    // wave-uniform: all 64 lanes in-range
#pragma unroll
          for (int r = 0; r < 4; r++) row[ub + r] = f2h(c4[r] + dv[r]);
        } else {
#pragma unroll
          for (int r = 0; r < 4; r++) {
            int u = ub + r;
            if ((unsigned)u < (unsigned)KC_) row[u] = f2h(c4[r] + dv[r]);
          }
        }
      }
    };
    {
      short8 ra0, ra1, rc0, rc1;
      floatx4 da, dc;
      rload(wv, ra0, ra1, da);
      rload(wv + 8, rc0, rc1, dc);
      rstore(wv, ra0, ra1, da);
      rload(wv + 16, ra0, ra1, da);
      rstore(wv + 8, rc0, rc1, dc);
      rload(wv + 24, rc0, rc1, dc);
      rstore(wv + 16, ra0, ra1, da);
      if (wv < 2) {
        rload(wv + 32, ra0, ra1, da);
        rstore(wv + 24, rc0, rc1, dc);
        rstore(wv + 32, ra0, ra1, da);
      } else {
        rstore(wv + 24, rc0, rc1, dc);
      }
    }
    // ---- kt0 K-frags issued pre-barrier: latency hides under barrier drain ----
    const unsigned short* kp = kw0 + (size_t)kc * HD_;
    short8 k0a = *(const short8*)(kp);
    short8 k0b = *(const short8*)(kp + 32);
    __syncthreads();                    // the only barrier in the chunk loop

    // ---- B'(c): content + R + exp2 + sum + write P; kt+1 prefetched ----
    auto bphase = [&](short8 a0, short8 a1, int kt) {
      int u0 = wv * 64 + kt * 16;
#pragma unroll
      for (int t = 0; t < 2; t++) {
        floatx4 c4 = (floatx4){0.f, 0.f, 0.f, 0.f};
        c4 = __builtin_amdgcn_mfma_f32_16x16x32_bf16(a0, bqw[t][0], c4, 0, 0, 0);
        c4 = __builtin_amdgcn_mfma_f32_16x16x32_bf16(a1, bqw[t][1], c4, 0, 0, 0);
        int q = t * 16 + lm;
        unsigned short* pp = &S[q * SP2 + u0 + lg * 4];
        ushort4 Rv = *(const ushort4*)pp;
        float p0 = exp2f(c4[0] + h2f(Rv.x));
        float p1 = exp2f(c4[1] + h2f(Rv.y));
        float p2 = exp2f(c4[2] + h2f(Rv.z));
        float p3 = exp2f(c4[3] + h2f(Rv.w));
        float ps = (p0 + p1) + (p2 + p3);
        if (t == 0) s0 += ps; else s1 += ps;
        unsigned w0, w1;
        asm("v_cvt_pk_bf16_f32 %0, %1, %2" : "=v"(w0) : "v"(p0), "v"(p1));
        asm("v_cvt_pk_bf16_f32 %0, %1, %2" : "=v"(w1) : "v"(p2), "v"(p3));
        *(uint2*)pp = make_uint2(w0, w1);
      }
    };
    short8 k1a = *(const short8*)(kp + 16 * HD_);
    short8 k1b = *(const short8*)(kp + 16 * HD_ + 32);
    bphase(k0a, k0b, 0);
    short8 k2a = *(const short8*)(kp + 32 * HD_);
    short8 k2b = *(const short8*)(kp + 32 * HD_ + 32);
    bphase(k1a, k1b, 1);
    short8 k3a = *(const short8*)(kp + 48 * HD_);
    short8 k3b = *(const short8*)(kp + 48 * HD_ + 32);
    bphase(k2a, k2b, 2);
    bphase(k3a, k3b, 3);

    // ---- D(c): O += P V (own-wave P columns; same-wave program order).
    //      P reads as 2x b64: dw-stride 258 = 2 mod 32 -> uniform banks. ----
#pragma unroll
    for (int s = 0; s < 2; s++) {
      int u0 = wv * 64 + s * 32;
      int e0 = lm * SP2 + u0 + lg * 8;
      int e1 = (16 + lm) * SP2 + u0 + lg * 8;
      uint2 x0 = *(const uint2*)&S[e0];
      uint2 x1 = *(const uint2*)&S[e0 + 4];
      uint2 y0 = *(const uint2*)&S[e1];
      uint2 y1 = *(const uint2*)&S[e1 + 4];
      uintx4 ua = {x0.x, x0.y, x1.x, x1.y};
      uintx4 ub = {y0.x, y0.y, y1.x, y1.y};
      short8 a0 = __builtin_bit_cast(short8, ua);
      short8 a1 = __builtin_bit_cast(short8, ub);
      const unsigned short* vp = vb0 + kc + u0 + lg * 8;
#pragma unroll
      for (int j = 0; j < 4; j++) {
        short8 bb = *(const short8*)&vp[(size_t)(j * 16 + lm) * S_];
        acc[0][j] = __builtin_amdgcn_mfma_f32_16x16x32_bf16(a0, bb, acc[0][j], 0, 0, 0);
        acc[1][j] = __builtin_amdgcn_mfma_f32_16x16x32_bf16(a1, bb, acc[1][j], 0, 0, 0);
      }
    }
  }
  // ---- tail: reduce exp-sums across lg (in-wave) then across waves ----
  s0 += __shfl_xor(s0, 16); s0 += __shfl_xor(s0, 32);
  s1 += __shfl_xor(s1, 16); s1 += __shfl_xor(s1, 32);
  if (lane < 16) { sSum[wv][lane] = s0; sSum[wv][16 + lane] = s1; }
  __syncthreads();                      // also: all D(3) P-reads done -> sS dead
  if (tid < 32) {
    float t = 0.f;
#pragma unroll
    for (int w = 0; w < 8; w++) t += sSum[w][tid];
    sLinv[tid] = 1.f / t;
  }
  float* po = (float*)sS;               // 8 waves x 2048 f32 = 64 KiB (fits dbuf)
#pragma unroll
  for (int m = 0; m < 2; m++)
#pragma unroll
    for (int j = 0; j < 4; j++)
#pragma unroll
      for (int r = 0; r < 4; r++) {
        int q = m * 16 + lg * 4 + r;
        int dh = j * 16 + lm;
        po[wv * 2048 + q * 64 + dh] = acc[m][j][r];
      }
  __syncthreads();
  {
    int e = tid * 4;                    // 512 threads x 4 = 2048 outputs
    int q = e >> 6, dh = e & 63;
    float4 v = *(float4*)&po[e];
#pragma unroll
    for (int w = 1; w < 8; w++) {
      float4 u = *(float4*)&po[w * 2048 + e];
      v.x += u.x; v.y += u.y; v.z += u.z; v.w += u.w;
    }
    float li = sLinv[q];
    ushort4 o = make_ushort4(f2bf(v.x * li), f2bf(v.y * li), f2bf(v.z * li), f2bf(v.w * li));
    *(ushort4*)&xb[(size_t)(b * S_ + q0 + q) * HD_ + h * 64 + dh] = o;
  }
}

extern "C" void kernel_launch(void* const* d_in, const int* in_sizes, int n_in,
                              void* d_out, int out_size, void* d_ws, size_t ws_size,
                              hipStream_t stream) {
  const float* inputs_q  = (const float*)d_in[0];
  const float* inputs_kv = (const float*)d_in[1];
  const float* pos_embed = (const float*)d_in[2];
  const float* Wq   = (const float*)d_in[3];
  const float* bq   = (const float*)d_in[4];
  const float* Wk   = (const float*)d_in[5];
  const float* bk   = (const float*)d_in[6];
  const float* Wv   = (const float*)d_in[7];
  const float* bv   = (const float*)d_in[8];
  const float* Wpos = (const float*)d_in[9];
  const float* rrb  = (const float*)d_in[10];
  const float* rwb  = (const float*)d_in[11];
  const float* Wout = (const float*)d_in[12];
  const float* bout = (const float*)d_in[13];
  float* out = (float*)d_out;

  char* ws = (char*)d_ws;                       // ~62 MB used
  unsigned short* aq  = (unsigned short*)(ws);                 // 8MB (reused as xb)
  unsigned short* akv = (unsigned short*)(ws + ( 8u << 20));   // 8MB
  unsigned short* apo = (unsigned short*)(ws + (16u << 20));   // 4MB
  unsigned short* wqt = (unsigned short*)(ws + (20u << 20));   // 2MB each
  unsigned short* wkt = (unsigned short*)(ws + (22u << 20));
  unsigned short* wvt = (unsigned short*)(ws + (24u << 20));
  unsigned short* wpt = (unsigned short*)(ws + (26u << 20));
  unsigned short* wot = (unsigned short*)(ws + (28u << 20));
  unsigned short* qwp = (unsigned short*)(ws + (30u << 20));   // 8MB
  float*          drp = (float*)(ws + (38u << 20));            // 128KB
  unsigned short* kbp = (unsigned short*)(ws + (46u << 20));   // 8MB
  unsigned short* vtp = (unsigned short*)(ws + (54u << 20));   // 8MB (vt layout)
  unsigned short* rbp = (unsigned short*)(ws + (62u << 20));   // 4MB
  unsigned short* xbp = aq;                                    // aq dead after q-GEMM

  PrepP pp;
  pp.sq = inputs_q; pp.skv = inputs_kv; pp.spos = pos_embed;
  pp.dq = aq; pp.dkv = akv; pp.dpos = apo;
  pp.ts[0] = Wq; pp.ts[1] = Wk; pp.ts[2] = Wv; pp.ts[3] = Wpos; pp.ts[4] = Wout;
  pp.td[0] = wqt; pp.td[1] = wkt; pp.td[2] = wvt; pp.td[3] = wpt; pp.td[4] = wot;
  prep_all<<<CAST_BLKS + 5120, 256, 0, stream>>>(pp);

  // all 4 projection GEMMs in ONE 896-block launch:
  //   [0,256): q mode1 -> qwp                 [256,384): rpos mode0 -> rbp
  //   [384,640): k mode0 -> kbp               [640,896): v mode4 -> vtp
  GP gp{};
  gp.s[0] = {aq,  wqt, bq,      rwb,     qwp,     nullptr, 1, 256};
  gp.s[1] = {apo, wpt, nullptr, nullptr, rbp,     nullptr, 0, 384};
  gp.s[2] = {akv, wkt, bk,      nullptr, kbp,     nullptr, 0, 640};
  gp.s[3] = {akv, wvt, bv,      nullptr, vtp,     nullptr, 4, 896};
  gemm_bt<<<896, 256, 0, stream>>>(gp, HD_, D_);

  drp_kernel<<<128, 256, 0, stream>>>(rbp, rrb, rwb, drp);

  attn_kernel<<<2048, 512, 0, stream>>>(qwp, kbp, rbp, vtp, drp, xbp);

  GP go{};
  go.s[0] = {xbp, wot, bout, nullptr, nullptr, out, 2, 256};
  go.s[1] = {nullptr, nullptr, nullptr, nullptr, nullptr, nullptr, 0, 1 << 30};
  go.s[2] = go.s[1];
  go.s[3] = go.s[1];
  gemm_bt<<<256, 256, 0, stream>>>(go, F_, HD_);
}